// Round 1
// baseline (379.094 us; speedup 1.0000x reference)
//
#include <hip/hip_runtime.h>
#include <math.h>

#define NN 500
#define NE 64
#define BATCH 8
#define RR 15
#define PW 31            // 2R+1
#define CAN 200
#define OHW 198

// ---------------------------------------------------------------------------
// K0: build pupil field, K*GAMMA table, and 500-pt twiddle table
// field[y][x] = INCIDENT * exp(i*phase) * exp(-i*C1)   (f64 constants -> f32)
// ---------------------------------------------------------------------------
__global__ void k_init(const float* __restrict__ phase,
                       float2* __restrict__ field,
                       float* __restrict__ kgamma,
                       float2* __restrict__ tw) {
    int idx = blockIdx.x * blockDim.x + threadIdx.x;
    if (idx < NN) {
        double th = 2.0 * M_PI * (double)idx / (double)NN;
        tw[idx] = make_float2((float)cos(th), (float)sin(th));
    }
    if (idx >= NN * NN) return;
    int i = idx / NN, j = idx % NN;

    // coordinates: _x = (k - 250) * 1e-6
    double x = (double)(j - 250) * 1e-6;
    double y = (double)(i - 250) * 1e-6;
    double r2 = x * x + y * y;
    double inc_d = exp(-r2 / (2.0 * 1.5e-4 * 1.5e-4));
    double c1 = fmod(M_PI / (5.32e-7 * 0.1) * r2, 2.0 * M_PI);
    float inc = (float)inc_d;
    float b1r = (float)cos(c1);
    float b1i = (float)(-sin(c1));
    float ph = phase[idx];
    float sp, cp;
    sincosf(ph, &sp, &cp);
    float ar = inc * cp, ai = inc * sp;
    field[idx] = make_float2(ar * b1r - ai * b1i, ar * b1i + ai * b1r);

    // fftfreq: k<250 -> k, else k-500 ; /(N*d) = *2000
    double fy = (double)((i < 250) ? i : i - 500) * 2000.0;
    double fx = (double)((j < 250) ? j : j - 500) * 2000.0;
    double a = 5.32e-7 * fx;     // RI*WL*freq  (A varies along columns)
    double b = 5.32e-7 * fy;
    double g = 1.0 - a * a - b * b;
    g = (g > 0.0) ? sqrt(g) : 0.0;
    float Kf = (float)(2.0 * M_PI * 1.0 / 5.32e-7);  // replicate f32(K)*f32(gamma)
    kgamma[idx] = Kf * (float)g;
}

// ---------------------------------------------------------------------------
// Generic 500-point direct DFT along one axis.
// line l: dst[l][k] = sum_n src[l][n] * exp(sgn * 2*pi*i * n*k/500)
// strides are in float2 elements.
// ---------------------------------------------------------------------------
__global__ void k_dft500(const float2* __restrict__ src, float2* __restrict__ dst,
                         const float2* __restrict__ tw,
                         int src_line, int src_elem, int dst_line, int dst_elem,
                         float sgn) {
    __shared__ float2 xs[NN];
    __shared__ float2 tt[NN];
    int line = blockIdx.x;
    const float2* s = src + (size_t)line * src_line;
    for (int n = threadIdx.x; n < NN; n += blockDim.x) {
        xs[n] = s[(size_t)n * src_elem];
        float2 t = tw[n];
        tt[n] = make_float2(t.x, sgn * t.y);
    }
    __syncthreads();
    float2* d = dst + (size_t)line * dst_line;
    for (int k = threadIdx.x; k < NN; k += blockDim.x) {
        float re = 0.f, im = 0.f;
        int idx = 0;
        for (int n = 0; n < NN; ++n) {
            float2 xv = xs[n];
            float2 w = tt[idx];
            re += xv.x * w.x - xv.y * w.y;
            im += xv.x * w.y + xv.y * w.x;
            idx += k; if (idx >= NN) idx -= NN;
        }
        d[(size_t)k * dst_elem] = make_float2(re, im);
    }
}

// ---------------------------------------------------------------------------
// B1: per (z,u): Y[v] = Ef[u,v]*exp(i*kgamma[u,v]*z);
//     part[z][c][u] = sum_v Y[v] * exp(+2*pi*i*v*c/500), c = 235..265
// ---------------------------------------------------------------------------
__global__ void k_prop_rows(const float2* __restrict__ Ef,
                            const float* __restrict__ kgamma,
                            const float* __restrict__ zs,
                            const float2* __restrict__ tw,
                            float2* __restrict__ part) {
    __shared__ float2 Y[NN];
    __shared__ float2 tt[NN];
    __shared__ float2 red[PW][8];
    int u = blockIdx.x;
    int z = blockIdx.y;
    float zv = zs[z];
    const float2* erow = Ef + (size_t)u * NN;
    const float* grow = kgamma + (size_t)u * NN;
    for (int v = threadIdx.x; v < NN; v += blockDim.x) {
        float th = grow[v] * zv;       // matches f32 (K*GAMMA)*z
        float s, c;
        sincosf(th, &s, &c);
        float2 e = erow[v];
        Y[v] = make_float2(e.x * c - e.y * s, e.x * s + e.y * c);
        tt[v] = tw[v];                 // inverse sign: +
    }
    __syncthreads();
    int t = threadIdx.x;
    if (t < PW * 8) {
        int ci = t >> 3, seg = t & 7;
        int c = 235 + ci;
        int idx = (seg * c) % NN;
        int step = (8 * c) % NN;
        float re = 0.f, im = 0.f;
        for (int v = seg; v < NN; v += 8) {
            float2 xv = Y[v];
            float2 w = tt[idx];
            re += xv.x * w.x - xv.y * w.y;
            im += xv.x * w.y + xv.y * w.x;
            idx += step; if (idx >= NN) idx -= NN;
        }
        red[ci][seg] = make_float2(re, im);
    }
    __syncthreads();
    if (t < PW) {
        float re = 0.f, im = 0.f;
        for (int s = 0; s < 8; ++s) { re += red[t][s].x; im += red[t][s].y; }
        part[((size_t)z * PW + t) * NN + u] = make_float2(re, im);
    }
}

// ---------------------------------------------------------------------------
// B2: per (z,c): Eprop[r,c] = (1/500^2) * sum_u part[z][c][u]*exp(+2*pi*i*u*r/500)
//     psf_raw[z][r][c] = |Eprop|^2
// ---------------------------------------------------------------------------
__global__ void k_prop_cols(const float2* __restrict__ part,
                            const float2* __restrict__ tw,
                            float* __restrict__ psf) {
    __shared__ float2 X[NN];
    __shared__ float2 tt[NN];
    __shared__ float2 red[PW][8];
    int ci = blockIdx.x;   // 31
    int z = blockIdx.y;    // 64
    const float2* col = part + ((size_t)z * PW + ci) * NN;
    for (int u = threadIdx.x; u < NN; u += blockDim.x) {
        X[u] = col[u];
        tt[u] = tw[u];
    }
    __syncthreads();
    int t = threadIdx.x;
    if (t < PW * 8) {
        int ri = t >> 3, seg = t & 7;
        int r = 235 + ri;
        int idx = (seg * r) % NN;
        int step = (8 * r) % NN;
        float re = 0.f, im = 0.f;
        for (int u = seg; u < NN; u += 8) {
            float2 xv = X[u];
            float2 w = tt[idx];
            re += xv.x * w.x - xv.y * w.y;
            im += xv.x * w.y + xv.y * w.x;
            idx += step; if (idx >= NN) idx -= NN;
        }
        red[ri][seg] = make_float2(re, im);
    }
    __syncthreads();
    if (t < PW) {
        float re = 0.f, im = 0.f;
        for (int s = 0; s < 8; ++s) { re += red[t][s].x; im += red[t][s].y; }
        const float inv = 1.0f / 250000.0f;
        re *= inv; im *= inv;
        psf[(size_t)z * (PW * PW) + t * PW + ci] = re * re + im * im;
    }
}

// ---------------------------------------------------------------------------
// B3: per-z PSF sum -> scale = 1e6/(sum+1e-12)
// ---------------------------------------------------------------------------
__global__ void k_norm(const float* __restrict__ psf, float* __restrict__ scales) {
    __shared__ float red[256];
    int z = blockIdx.x;
    float s = 0.f;
    for (int p = threadIdx.x; p < PW * PW; p += 256) s += psf[z * PW * PW + p];
    red[threadIdx.x] = s;
    __syncthreads();
    for (int o = 128; o > 0; o >>= 1) {
        if (threadIdx.x < o) red[threadIdx.x] += red[threadIdx.x + o];
        __syncthreads();
    }
    if (threadIdx.x == 0) scales[z] = 1.0e6f / (red[0] + 1e-12f);
}

// ---------------------------------------------------------------------------
// Blur kernel coefficients from std_u
// ---------------------------------------------------------------------------
__global__ void k_kern(const float* __restrict__ std_u, float* __restrict__ kern) {
    int t = threadIdx.x;
    if (t < 49) {
        float stdv = 0.8f + 0.4f * std_u[0];
        float s2 = stdv * stdv;
        int a = t / 7 - 3, b = t % 7 - 3;
        float g = (float)exp(-0.5 * (double)(a * a + b * b));  // GAUSS7 (f64->f32)
        kern[t] = (1.0f / (2.0f * (float)M_PI * s2)) * powf(g, 1.0f / s2);
    }
}

__global__ void k_zero(float* __restrict__ p, int n) {
    int i = blockIdx.x * blockDim.x + threadIdx.x;
    if (i < n) p[i] = 0.f;
}

// ---------------------------------------------------------------------------
// Scatter-add PSFs onto canvases
// ---------------------------------------------------------------------------
__global__ void k_scatter(const float* __restrict__ psf,
                          const float* __restrict__ scales,
                          const int* __restrict__ xyz,
                          float* __restrict__ canvas) {
    int e = blockIdx.x;   // 64
    int b = blockIdx.y;   // 8
    int r0 = xyz[(b * NE + e) * 2 + 0] - RR;
    int c0 = xyz[(b * NE + e) * 2 + 1] - RR;
    float sc = scales[e];
    float* cb = canvas + (size_t)b * (CAN * CAN);
    for (int p = threadIdx.x; p < PW * PW; p += blockDim.x) {
        int i = p / PW, j = p % PW;
        atomicAdd(cb + (r0 + i) * CAN + (c0 + j), psf[e * PW * PW + p] * sc);
    }
}

// ---------------------------------------------------------------------------
// 7x7 blur (zero-padded, pad=2 -> 198x198) + sensor noise chain
// ---------------------------------------------------------------------------
__global__ void k_final(const float* __restrict__ canvas,
                        const float* __restrict__ kern,
                        const float* __restrict__ eps_dark,
                        const float* __restrict__ eps_photon,
                        const float* __restrict__ eps_read,
                        float* __restrict__ out) {
    __shared__ float kk[49];
    if (threadIdx.x < 49) kk[threadIdx.x] = kern[threadIdx.x];
    __syncthreads();
    int idx = blockIdx.x * blockDim.x + threadIdx.x;
    if (idx >= BATCH * OHW * OHW) return;
    int b = idx / (OHW * OHW);
    int rem = idx % (OHW * OHW);
    int i = rem / OHW, j = rem % OHW;
    const float* cb = canvas + (size_t)b * (CAN * CAN);
    float acc = 0.f;
#pragma unroll
    for (int a = 0; a < 7; ++a) {
        int r = i + a - 2;
        if (r < 0 || r >= CAN) continue;
#pragma unroll
        for (int q = 0; q < 7; ++q) {
            int c = j + q - 2;
            if (c < 0 || c >= CAN) continue;
            acc += cb[r * CAN + c] * kk[a * 7 + q];
        }
    }
    float sig = acc * 0.9f;
    float dark = 0.005f + eps_dark[idx] * sqrtf(0.005f);
    float total = fmaxf(sig + dark, 0.0f);
    float noisy = total + eps_photon[idx] * sqrtf(fmaxf(total, 1e-12f));
    float elec = noisy + eps_read[idx] * 1.6f;
    float adu = fminf(fmaxf(elec * 2.0f, 0.0f), 65535.0f);
    float v = (adu <= 10.0f) ? 1.0f : fminf(adu, 4.0e9f);
    out[idx] = v / 4.0e9f;
}

// ---------------------------------------------------------------------------
extern "C" void kernel_launch(void* const* d_in, const int* in_sizes, int n_in,
                              void* d_out, int out_size, void* d_ws, size_t ws_size,
                              hipStream_t stream) {
    const float* phase    = (const float*)d_in[0];   // 500*500
    const float* zs       = (const float*)d_in[1];   // 64
    const int*   xyz      = (const int*)d_in[2];     // 8*64*2
    const float* std_u    = (const float*)d_in[3];   // 1
    const float* epsd     = (const float*)d_in[4];   // 8*198*198
    const float* epsp     = (const float*)d_in[5];
    const float* epsr     = (const float*)d_in[6];
    float* out = (float*)d_out;

    char* ws = (char*)d_ws;
    size_t off = 0;
    auto alloc = [&](size_t bytes) {
        off = (off + 255) & ~(size_t)255;
        size_t o = off; off += bytes; return o;
    };
    float2* field  = (float2*)(ws + alloc((size_t)NN * NN * 8));
    float*  kgamma = (float*) (ws + alloc((size_t)NN * NN * 4));
    float2* tw     = (float2*)(ws + alloc((size_t)NN * 8));
    float2* R1     = (float2*)(ws + alloc((size_t)NN * NN * 8));
    float2* Ef     = (float2*)(ws + alloc((size_t)NN * NN * 8));
    float2* part   = (float2*)(ws + alloc((size_t)NE * PW * NN * 8));
    float*  psf    = (float*) (ws + alloc((size_t)NE * PW * PW * 4));
    float*  scales = (float*) (ws + alloc((size_t)NE * 4));
    float*  kern   = (float*) (ws + alloc((size_t)64 * 4));
    float*  canvas = (float*) (ws + alloc((size_t)BATCH * CAN * CAN * 4));
    (void)ws_size; (void)n_in; (void)in_sizes; (void)out_size;

    k_init<<<dim3((NN * NN + 255) / 256), 256, 0, stream>>>(phase, field, kgamma, tw);
    // fft2: rows then cols (both forward, sign=-1)
    k_dft500<<<NN, 256, 0, stream>>>(field, R1, tw, NN, 1, NN, 1, -1.0f);
    k_dft500<<<NN, 256, 0, stream>>>(R1, Ef, tw, 1, NN, 1, NN, -1.0f);
    // partial inverse transforms for the 31x31 crop, all 64 z-planes
    k_prop_rows<<<dim3(NN, NE), 256, 0, stream>>>(Ef, kgamma, zs, tw, part);
    k_prop_cols<<<dim3(PW, NE), 256, 0, stream>>>(part, tw, psf);
    k_norm<<<NE, 256, 0, stream>>>(psf, scales);
    k_kern<<<1, 64, 0, stream>>>(std_u, kern);
    k_zero<<<(BATCH * CAN * CAN + 255) / 256, 256, 0, stream>>>(canvas, BATCH * CAN * CAN);
    k_scatter<<<dim3(NE, BATCH), 256, 0, stream>>>(psf, scales, xyz, canvas);
    k_final<<<(BATCH * OHW * OHW + 255) / 256, 256, 0, stream>>>(canvas, kern, epsd, epsp, epsr, out);
}

// Round 2
// 288.252 us; speedup vs baseline: 1.3151x; 1.3151x over previous
//
#include <hip/hip_runtime.h>
#include <math.h>

#define NN 500
#define NE 64
#define BATCH 8
#define RR 15
#define PW 31            // 2R+1
#define CAN 200
#define OHW 198
#define TWO_PI_F 6.28318530717958647692f

// ---------------------------------------------------------------------------
// K0: build pupil field, K*GAMMA table, and 500-pt twiddle table
// ---------------------------------------------------------------------------
__global__ void k_init(const float* __restrict__ phase,
                       float2* __restrict__ field,
                       float* __restrict__ kgamma,
                       float2* __restrict__ tw) {
    int idx = blockIdx.x * blockDim.x + threadIdx.x;
    if (idx < NN) {
        double th = 2.0 * M_PI * (double)idx / (double)NN;
        tw[idx] = make_float2((float)cos(th), (float)sin(th));
    }
    if (idx >= NN * NN) return;
    int i = idx / NN, j = idx % NN;

    double x = (double)(j - 250) * 1e-6;
    double y = (double)(i - 250) * 1e-6;
    double r2 = x * x + y * y;
    double inc_d = exp(-r2 / (2.0 * 1.5e-4 * 1.5e-4));
    double c1 = fmod(M_PI / (5.32e-7 * 0.1) * r2, 2.0 * M_PI);
    float inc = (float)inc_d;
    float b1r = (float)cos(c1);
    float b1i = (float)(-sin(c1));
    float ph = phase[idx];
    float sp, cp;
    sincosf(ph, &sp, &cp);
    float ar = inc * cp, ai = inc * sp;
    field[idx] = make_float2(ar * b1r - ai * b1i, ar * b1i + ai * b1r);

    double fy = (double)((i < 250) ? i : i - 500) * 2000.0;
    double fx = (double)((j < 250) ? j : j - 500) * 2000.0;
    double a = 5.32e-7 * fx;
    double b = 5.32e-7 * fy;
    double g = 1.0 - a * a - b * b;
    g = (g > 0.0) ? sqrt(g) : 0.0;
    float Kf = (float)(2.0 * M_PI * 1.0 / 5.32e-7);
    kgamma[idx] = Kf * (float)g;
}

// ---------------------------------------------------------------------------
// Full 500-pt DFT along one axis, pair trick (k and k+250 share a rotator via
// (-1)^n), rotation recurrence with exact-table resync every 64 n.
// ---------------------------------------------------------------------------
__global__ void k_dft500(const float2* __restrict__ src, float2* __restrict__ dst,
                         const float2* __restrict__ tw,
                         int src_line, int src_elem, int dst_line, int dst_elem,
                         float sgn) {
    __shared__ __align__(16) float2 xs[NN];
    __shared__ float2 tts[NN];
    int line = blockIdx.x;
    const float2* s = src + (size_t)line * src_line;
    for (int n = threadIdx.x; n < NN; n += blockDim.x) {
        xs[n] = s[(size_t)n * src_elem];
        float2 t = tw[n];
        tts[n] = make_float2(t.x, sgn * t.y);
    }
    __syncthreads();
    int k = threadIdx.x;
    if (k < 250) {
        // step twiddle e^{sgn*2pi*i*k/500}
        float2 s1 = tts[k];
        float wr = 1.f, wi = 0.f;
        float a1r = 0.f, a1i = 0.f, a2r = 0.f, a2i = 0.f;
        for (int n = 0; n < NN; n += 2) {
            if ((n & 63) == 0) {   // resync rotator from exact table
                int idx = (n * k) % NN;
                float2 e = tts[idx];
                wr = e.x; wi = e.y;
            }
            float4 xy = *(const float4*)&xs[n];   // xs[n], xs[n+1]
            float tr = wr * s1.x - wi * s1.y;     // w * s1   (twiddle at n+1)
            float ti = wr * s1.y + wi * s1.x;
            float pr = xy.x * wr - xy.y * wi;
            float pi = xy.x * wi + xy.y * wr;
            float qr = xy.z * tr - xy.w * ti;
            float qi = xy.z * ti + xy.w * tr;
            a1r += pr + qr;  a1i += pi + qi;
            a2r += pr - qr;  a2i += pi - qi;      // output k+250: *(-1)^n
            wr = tr * s1.x - ti * s1.y;           // advance to n+2
            wi = tr * s1.y + ti * s1.x;
        }
        float2* d = dst + (size_t)line * dst_line;
        d[(size_t)k * dst_elem] = make_float2(a1r, a1i);
        d[(size_t)(k + 250) * dst_elem] = make_float2(a2r, a2i);
    }
}

// ---------------------------------------------------------------------------
// B1: per (u, zhalf) block: stage Ef row + kgamma row, then for 4 groups of
// 8 z-planes: modulate into LDS, partial DFT over v for c=235..265 with a
// per-thread rotation recurrence, 8 z accumulators per thread, shuffle-reduce.
//   part[z][c][u] = sum_v Ef[u,v]*e^{i*kg[u,v]*z} * e^{+2pi*i*v*c/500}
// ---------------------------------------------------------------------------
__global__ void k_prop_rows(const float2* __restrict__ Ef,
                            const float* __restrict__ kgamma,
                            const float* __restrict__ zs,
                            float2* __restrict__ part) {
    __shared__ float2 Ys[8][NN];    // 32 KB
    __shared__ float2 efs[NN];      // 4 KB
    __shared__ float  kgs[NN];      // 2 KB
    int u = blockIdx.x;
    int zhalf = blockIdx.y;         // 0/1 -> z in [zhalf*32, zhalf*32+32)
    int t = threadIdx.x;

    const float2* erow = Ef + (size_t)u * NN;
    const float* grow = kgamma + (size_t)u * NN;
    for (int v = t; v < NN; v += 256) {
        efs[v] = erow[v];
        kgs[v] = grow[v];
    }

    // per-thread DFT role (fixed across groups)
    int ci = t >> 3, seg = t & 7;          // ci 0..31 (31 used), seg 0..7
    int c = 235 + ci;
    float w0r = 0.f, w0i = 0.f, sr = 0.f, si = 0.f;
    if (t < PW * 8) {
        float th0 = (TWO_PI_F / NN) * (float)((seg * c) % NN);
        sincosf(th0, &w0i, &w0r);
        float ths = (TWO_PI_F / NN) * (float)((8 * c) % NN);
        sincosf(ths, &si, &sr);
    }
    __syncthreads();

    for (int g = 0; g < 4; ++g) {
        int zbase = zhalf * 32 + g * 8;
        float zv[8];
#pragma unroll
        for (int zi = 0; zi < 8; ++zi) zv[zi] = zs[zbase + zi];
        // modulate: Ys[zi][v] = efs[v] * e^{i*kgs[v]*z}
        for (int v = t; v < NN; v += 256) {
            float2 e = efs[v];
            float kg = kgs[v];
#pragma unroll
            for (int zi = 0; zi < 8; ++zi) {
                float s, cc;
                sincosf(kg * zv[zi], &s, &cc);
                Ys[zi][v] = make_float2(e.x * cc - e.y * s, e.x * s + e.y * cc);
            }
        }
        __syncthreads();

        if (t < PW * 8) {
            float wr = w0r, wi = w0i;
            float2 acc[8];
#pragma unroll
            for (int zi = 0; zi < 8; ++zi) acc[zi] = make_float2(0.f, 0.f);
            for (int v = seg; v < NN; v += 8) {
#pragma unroll
                for (int zi = 0; zi < 8; ++zi) {
                    float2 xv = Ys[zi][v];
                    acc[zi].x += xv.x * wr - xv.y * wi;
                    acc[zi].y += xv.x * wi + xv.y * wr;
                }
                float nwr = wr * sr - wi * si;
                wi = wr * si + wi * sr;
                wr = nwr;
            }
            // reduce over seg (8 consecutive lanes)
#pragma unroll
            for (int zi = 0; zi < 8; ++zi) {
#pragma unroll
                for (int m = 1; m < 8; m <<= 1) {
                    acc[zi].x += __shfl_xor(acc[zi].x, m);
                    acc[zi].y += __shfl_xor(acc[zi].y, m);
                }
            }
            if (seg == 0 && ci < PW) {
#pragma unroll
                for (int zi = 0; zi < 8; ++zi) {
                    part[((size_t)(zbase + zi) * PW + ci) * NN + u] = acc[zi];
                }
            }
        }
        __syncthreads();
    }
}

// ---------------------------------------------------------------------------
// B2: per (z,c): Eprop[r,c] = (1/500^2) * sum_u part[z][c][u]*e^{+2pi*i*u*r/500}
// rotation recurrence + shuffle reduce; psf = |Eprop|^2
// ---------------------------------------------------------------------------
__global__ void k_prop_cols(const float2* __restrict__ part,
                            float* __restrict__ psf) {
    __shared__ float2 X[NN];
    int ci = blockIdx.x;   // 31
    int z = blockIdx.y;    // 64
    int t = threadIdx.x;
    const float2* col = part + ((size_t)z * PW + ci) * NN;
    for (int u = t; u < NN; u += 256) X[u] = col[u];
    __syncthreads();
    if (t < PW * 8) {
        int ri = t >> 3, seg = t & 7;
        int r = 235 + ri;
        float wr, wi, sr, si;
        {
            float th0 = (TWO_PI_F / NN) * (float)((seg * r) % NN);
            sincosf(th0, &wi, &wr);
            float ths = (TWO_PI_F / NN) * (float)((8 * r) % NN);
            sincosf(ths, &si, &sr);
        }
        float ar = 0.f, ai = 0.f;
        for (int u = seg; u < NN; u += 8) {
            float2 xv = X[u];
            ar += xv.x * wr - xv.y * wi;
            ai += xv.x * wi + xv.y * wr;
            float nwr = wr * sr - wi * si;
            wi = wr * si + wi * sr;
            wr = nwr;
        }
#pragma unroll
        for (int m = 1; m < 8; m <<= 1) {
            ar += __shfl_xor(ar, m);
            ai += __shfl_xor(ai, m);
        }
        if (seg == 0 && ri < PW) {
            const float inv = 1.0f / 250000.0f;
            float re = ar * inv, im = ai * inv;
            psf[(size_t)z * (PW * PW) + ri * PW + ci] = re * re + im * im;
        }
    }
}

// ---------------------------------------------------------------------------
__global__ void k_norm(const float* __restrict__ psf, float* __restrict__ scales) {
    __shared__ float red[256];
    int z = blockIdx.x;
    float s = 0.f;
    for (int p = threadIdx.x; p < PW * PW; p += 256) s += psf[z * PW * PW + p];
    red[threadIdx.x] = s;
    __syncthreads();
    for (int o = 128; o > 0; o >>= 1) {
        if (threadIdx.x < o) red[threadIdx.x] += red[threadIdx.x + o];
        __syncthreads();
    }
    if (threadIdx.x == 0) scales[z] = 1.0e6f / (red[0] + 1e-12f);
}

__global__ void k_kern(const float* __restrict__ std_u, float* __restrict__ kern) {
    int t = threadIdx.x;
    if (t < 49) {
        float stdv = 0.8f + 0.4f * std_u[0];
        float s2 = stdv * stdv;
        int a = t / 7 - 3, b = t % 7 - 3;
        float g = (float)exp(-0.5 * (double)(a * a + b * b));
        kern[t] = (1.0f / (2.0f * (float)M_PI * s2)) * powf(g, 1.0f / s2);
    }
}

__global__ void k_zero(float* __restrict__ p, int n) {
    int i = blockIdx.x * blockDim.x + threadIdx.x;
    if (i < n) p[i] = 0.f;
}

__global__ void k_scatter(const float* __restrict__ psf,
                          const float* __restrict__ scales,
                          const int* __restrict__ xyz,
                          float* __restrict__ canvas) {
    int e = blockIdx.x;
    int b = blockIdx.y;
    int r0 = xyz[(b * NE + e) * 2 + 0] - RR;
    int c0 = xyz[(b * NE + e) * 2 + 1] - RR;
    float sc = scales[e];
    float* cb = canvas + (size_t)b * (CAN * CAN);
    for (int p = threadIdx.x; p < PW * PW; p += blockDim.x) {
        int i = p / PW, j = p % PW;
        atomicAdd(cb + (r0 + i) * CAN + (c0 + j), psf[e * PW * PW + p] * sc);
    }
}

__global__ void k_final(const float* __restrict__ canvas,
                        const float* __restrict__ kern,
                        const float* __restrict__ eps_dark,
                        const float* __restrict__ eps_photon,
                        const float* __restrict__ eps_read,
                        float* __restrict__ out) {
    __shared__ float kk[49];
    if (threadIdx.x < 49) kk[threadIdx.x] = kern[threadIdx.x];
    __syncthreads();
    int idx = blockIdx.x * blockDim.x + threadIdx.x;
    if (idx >= BATCH * OHW * OHW) return;
    int b = idx / (OHW * OHW);
    int rem = idx % (OHW * OHW);
    int i = rem / OHW, j = rem % OHW;
    const float* cb = canvas + (size_t)b * (CAN * CAN);
    float acc = 0.f;
#pragma unroll
    for (int a = 0; a < 7; ++a) {
        int r = i + a - 2;
        if (r < 0 || r >= CAN) continue;
#pragma unroll
        for (int q = 0; q < 7; ++q) {
            int c = j + q - 2;
            if (c < 0 || c >= CAN) continue;
            acc += cb[r * CAN + c] * kk[a * 7 + q];
        }
    }
    float sig = acc * 0.9f;
    float dark = 0.005f + eps_dark[idx] * sqrtf(0.005f);
    float total = fmaxf(sig + dark, 0.0f);
    float noisy = total + eps_photon[idx] * sqrtf(fmaxf(total, 1e-12f));
    float elec = noisy + eps_read[idx] * 1.6f;
    float adu = fminf(fmaxf(elec * 2.0f, 0.0f), 65535.0f);
    float v = (adu <= 10.0f) ? 1.0f : fminf(adu, 4.0e9f);
    out[idx] = v / 4.0e9f;
}

// ---------------------------------------------------------------------------
extern "C" void kernel_launch(void* const* d_in, const int* in_sizes, int n_in,
                              void* d_out, int out_size, void* d_ws, size_t ws_size,
                              hipStream_t stream) {
    const float* phase    = (const float*)d_in[0];
    const float* zs       = (const float*)d_in[1];
    const int*   xyz      = (const int*)d_in[2];
    const float* std_u    = (const float*)d_in[3];
    const float* epsd     = (const float*)d_in[4];
    const float* epsp     = (const float*)d_in[5];
    const float* epsr     = (const float*)d_in[6];
    float* out = (float*)d_out;

    char* ws = (char*)d_ws;
    size_t off = 0;
    auto alloc = [&](size_t bytes) {
        off = (off + 255) & ~(size_t)255;
        size_t o = off; off += bytes; return o;
    };
    float2* field  = (float2*)(ws + alloc((size_t)NN * NN * 8));
    float*  kgamma = (float*) (ws + alloc((size_t)NN * NN * 4));
    float2* tw     = (float2*)(ws + alloc((size_t)NN * 8));
    float2* R1     = (float2*)(ws + alloc((size_t)NN * NN * 8));
    float2* Ef     = (float2*)(ws + alloc((size_t)NN * NN * 8));
    float2* part   = (float2*)(ws + alloc((size_t)NE * PW * NN * 8));
    float*  psf    = (float*) (ws + alloc((size_t)NE * PW * PW * 4));
    float*  scales = (float*) (ws + alloc((size_t)NE * 4));
    float*  kern   = (float*) (ws + alloc((size_t)64 * 4));
    float*  canvas = (float*) (ws + alloc((size_t)BATCH * CAN * CAN * 4));
    (void)ws_size; (void)n_in; (void)in_sizes; (void)out_size;

    k_init<<<dim3((NN * NN + 255) / 256), 256, 0, stream>>>(phase, field, kgamma, tw);
    // fft2: rows then cols (forward, sign=-1)
    k_dft500<<<NN, 256, 0, stream>>>(field, R1, tw, NN, 1, NN, 1, -1.0f);
    k_dft500<<<NN, 256, 0, stream>>>(R1, Ef, tw, 1, NN, 1, NN, -1.0f);
    // partial inverse transforms for the 31x31 crop, all 64 z-planes
    k_prop_rows<<<dim3(NN, 2), 256, 0, stream>>>(Ef, kgamma, zs, part);
    k_prop_cols<<<dim3(PW, NE), 256, 0, stream>>>(part, psf);
    k_norm<<<NE, 256, 0, stream>>>(psf, scales);
    k_kern<<<1, 64, 0, stream>>>(std_u, kern);
    k_zero<<<(BATCH * CAN * CAN + 255) / 256, 256, 0, stream>>>(canvas, BATCH * CAN * CAN);
    k_scatter<<<dim3(NE, BATCH), 256, 0, stream>>>(psf, scales, xyz, canvas);
    k_final<<<(BATCH * OHW * OHW + 255) / 256, 256, 0, stream>>>(canvas, kern, epsd, epsp, epsr, out);
}